// Round 9
// baseline (94.390 us; speedup 1.0000x reference)
//
#include <hip/hip_runtime.h>
#include <hip/hip_bf16.h>

typedef float f32x4 __attribute__((ext_vector_type(4)));
typedef float f32x16 __attribute__((ext_vector_type(16)));
typedef __bf16 bf16x8 __attribute__((ext_vector_type(8)));

#define MFMA16(a, b, c) __builtin_amdgcn_mfma_f32_16x16x32_bf16((a), (b), (c), 0, 0, 0)
#define MFMA32(a, b, c) __builtin_amdgcn_mfma_f32_32x32x16_bf16((a), (b), (c), 0, 0, 0)

static __device__ __forceinline__ short f2s(float f) {
    __hip_bfloat16 h = __float2bfloat16(f);
    return *reinterpret_cast<short*>(&h);
}
static __device__ __forceinline__ unsigned int cvtpk(float lo, float hi) {
    unsigned int r;
    asm("v_cvt_pk_bf16_f32 %0, %1, %2" : "=v"(r) : "v"(lo), "v"(hi));
    return r;
}
static __device__ __forceinline__ float exp2f_fast(float x) {
#if __has_builtin(__builtin_amdgcn_exp2f)
    return __builtin_amdgcn_exp2f(x);
#else
    return exp2f(x);
#endif
}

// ---------------------------------------------------------------------------
// Kernel 0: gather adj int32 -> u8 codes in wave order (coalesced reads).
// Target layout (verified round-8): word at
//   adjG[((b*32+qt)*16 + t)*512 + i*64 + lane]
// holds codes for q = qt*32 + (lane&31),
//   k = t*64 + (i>>2)*32 + (i&3)*8 + (lane>>5)*4 + {0..3}.
// Writer: thread tid handles k0 = tid*4 of row q = qt*32 + j:
//   t = tid>>4, i = (tid>>1)&7, lane = j + 32*(tid&1).
// Reads: row-contiguous int4 (256 threads cover one 4KB row).  Grid z splits
// the 32 rows into 4 chunks of 8 for occupancy.
// ---------------------------------------------------------------------------
__global__ __launch_bounds__(256)
void adj_gather(const int* __restrict__ adj, unsigned int* __restrict__ adjG)
{
    const int tid = threadIdx.x;
    const int qt = blockIdx.x;            // 0..31
    const int b  = blockIdx.y;            // 0..7
    const int j0 = blockIdx.z * 8;        // q-row chunk

    const int4* base = reinterpret_cast<const int4*>(
        adj + ((size_t)(b * 1024 + qt * 32)) * 1024);
    unsigned int* outT = adjG + ((size_t)(b * 32 + qt)) * 16 * 512;

    const int t = tid >> 4;
    const int i = (tid >> 1) & 7;
    const int laneb = 32 * (tid & 1);

#pragma unroll
    for (int jj = 0; jj < 8; ++jj) {
        const int j = j0 + jj;
        const int4 c = base[j * 256 + tid];
        const unsigned int packed =
            (unsigned)c.x | ((unsigned)c.y << 8) | ((unsigned)c.z << 16) | ((unsigned)c.w << 24);
        outT[t * 512 + i * 64 + (j + laneb)] = packed;
    }
}

// ---------------------------------------------------------------------------
// Kernel 1: QKV projection (unchanged, verified).
// ---------------------------------------------------------------------------
__global__ __launch_bounds__(256)
void qkv_gemm(const float* __restrict__ x,
              const float* __restrict__ Wq, const float* __restrict__ bq,
              const float* __restrict__ Wk, const float* __restrict__ bk,
              const float* __restrict__ Wv, const float* __restrict__ bv,
              short* __restrict__ Qb, short* __restrict__ Kb, short* __restrict__ Vb)
{
    __shared__ short As[128 * 72];
    __shared__ short Bs[64 * 72];

    const int tid = threadIdx.x;
    const int lane = tid & 63;
    const int wid = tid >> 6;
    const int wr = wid >> 1, wc = wid & 1;
    const int g = lane >> 4, li = lane & 15;

    const int m0 = blockIdx.x * 128;
    const int gc0 = blockIdx.y * 64;
    const int mat = gc0 >> 8;
    const float* W    = (mat == 0) ? Wq : (mat == 1) ? Wk : Wv;
    const float* bias = (mat == 0) ? bq : (mat == 1) ? bk : bv;
    short* Out        = (mat == 0) ? Qb : (mat == 1) ? Kb : Vb;
    const int wc0 = gc0 & 255;

    f32x4 acc[4][2] = {};

    const int sr = tid >> 4;
    const int sc4 = (tid & 15) * 4;

    for (int k0 = 0; k0 < 256; k0 += 64) {
        __syncthreads();
#pragma unroll
        for (int it = 0; it < 8; ++it) {
            int row = sr + it * 16;
            float4 v = *reinterpret_cast<const float4*>(&x[(m0 + row) * 256 + k0 + sc4]);
            short4 s4;
            s4.x = f2s(v.x); s4.y = f2s(v.y); s4.z = f2s(v.z); s4.w = f2s(v.w);
            *reinterpret_cast<short4*>(&As[row * 72 + sc4]) = s4;
        }
#pragma unroll
        for (int it = 0; it < 4; ++it) {
            int row = sr + it * 16;
            float4 v = *reinterpret_cast<const float4*>(&W[(wc0 + row) * 256 + k0 + sc4]);
            short4 s4;
            s4.x = f2s(v.x); s4.y = f2s(v.y); s4.z = f2s(v.z); s4.w = f2s(v.w);
            *reinterpret_cast<short4*>(&Bs[row * 72 + sc4]) = s4;
        }
        __syncthreads();
#pragma unroll
        for (int ks = 0; ks < 2; ++ks) {
            const int kb = ks * 32 + g * 8;
            bf16x8 a[4], bfr[2];
#pragma unroll
            for (int i = 0; i < 4; ++i)
                a[i] = *reinterpret_cast<const bf16x8*>(&As[(wr * 64 + i * 16 + li) * 72 + kb]);
#pragma unroll
            for (int j = 0; j < 2; ++j)
                bfr[j] = *reinterpret_cast<const bf16x8*>(&Bs[(wc * 32 + j * 16 + li) * 72 + kb]);
#pragma unroll
            for (int i = 0; i < 4; ++i)
#pragma unroll
                for (int j = 0; j < 2; ++j)
                    acc[i][j] = MFMA16(a[i], bfr[j], acc[i][j]);
        }
    }

#pragma unroll
    for (int j = 0; j < 2; ++j) {
        const int colW = wc0 + wc * 32 + j * 16 + li;
        const int h = colW >> 5, d = colW & 31;
        const float bv_ = bias[colW];
#pragma unroll
        for (int i = 0; i < 4; ++i) {
#pragma unroll
            for (int r = 0; r < 4; ++r) {
                const int row = m0 + wr * 64 + i * 16 + g * 4 + r;
                const int bb = row >> 10, nq = row & 1023;
                Out[((bb * 8 + h) * 1024 + nq) * 32 + d] = f2s(acc[i][j][r] + bv_);
            }
        }
    }
}

// ---------------------------------------------------------------------------
// Kernel 2: edge-biased flash attention, 8-wave split-k structure.
// Grid (8, 64) swizzled; block 512 = 8 waves: wave = (kh = wid>>2, qw = wid&3).
// Wave (kh,qw) processes q-tile qb*4+qw over k-tiles [kh*8, kh*8+8).
// K/V^T double-buffered per k-half in LDS (padded strides 38 / 74 shorts ->
// bijective bank maps).  One barrier/iter; 2-way flash merge in epilogue.
// Softmax/PV math verbatim from verified round-7/8 kernels.
// ---------------------------------------------------------------------------
__global__ __launch_bounds__(512)
void attn5(const short* __restrict__ Qb, const short* __restrict__ Kb,
           const short* __restrict__ Vb, const unsigned int* __restrict__ adjG,
           const float* __restrict__ edge_emb, short* __restrict__ AO)
{
    // Ks[buf][half]: 64 rows x 38 shorts (2432); Vt[buf][half]: 32 x 74 (2368)
    __shared__ __align__(16) short LDSBUF[4 * 2432 + 4 * 2368];   // 38400 B
    __shared__ float Etab[8];

    const int tid = threadIdx.x, lane = tid & 63, wid = tid >> 6;
    const int qw = wid & 3, kh = wid >> 2;
    const int l5 = lane & 31, h32 = lane >> 5;

    // bijective chunked XCD swizzle (512 blocks = 8 XCD x 64)
    const int orig = blockIdx.x + blockIdx.y * 8;
    const int flat = (orig & 7) * 64 + (orig >> 3);
    const int qb = flat & 7, bh = flat >> 3;
    const int b = bh >> 3, h = bh & 7;
    const int qt = qb * 4 + qw;
    const int q  = qt * 32 + l5;

    const short* Qh = Qb + bh * (1024 * 32);
    const short* Kh = Kb + bh * (1024 * 32);
    const short* Vh = Vb + bh * (1024 * 32);
    const unsigned int* adjT = adjG + ((size_t)(b * 32 + qt)) * 16 * 512;

    if (tid < 5) Etab[tid] = __expf(edge_emb[tid * 8 + h]);

    const bf16x8 qf0 = *reinterpret_cast<const bf16x8*>(&Qh[q * 32 + h32 * 8]);
    const bf16x8 qf1 = *reinterpret_cast<const bf16x8*>(&Qh[q * 32 + 16 + h32 * 8]);

    const float c1 = 0.25503486f;   // log2(e)/sqrt(32)
    const f32x16 zero16 = {};

    f32x16 o = {};
    float m2 = -1e30f, l_run = 0.f;

    // staging map: 256 threads per half; st = tid&255, sh = tid>>8
    const int st = tid & 255, sh = tid >> 8;
    const int sr = st >> 2;          // k-row 0..63
    const int sc = (st & 3) * 8;     // d-chunk (shorts)

    short* const KsB = LDSBUF;                 // + (buf*2+half)*2432
    short* const VtB = LDSBUF + 4 * 2432;      // + (buf*2+half)*2368

    // prologue: stage tile (sh*8) into buf 0
    {
        const int row = sh * 512 + sr;
        int4 kr = *reinterpret_cast<const int4*>(&Kh[row * 32 + sc]);
        int4 vr = *reinterpret_cast<const int4*>(&Vh[row * 32 + sc]);
        short* kd = KsB + sh * 2432 + sr * 38 + sc;
        *reinterpret_cast<short4*>(kd)     = *reinterpret_cast<short4*>(&kr);
        *reinterpret_cast<short4*>(kd + 4) = *(reinterpret_cast<short4*>(&kr) + 1);
        short* vd = VtB + sh * 2368;
        const short* vs = reinterpret_cast<const short*>(&vr);
#pragma unroll
        for (int i = 0; i < 8; ++i) vd[(sc + i) * 74 + sr] = vs[i];
    }
    __syncthreads();

    for (int t = 0; t < 8; ++t) {
        const int cur = t & 1;
        const int tt = kh * 8 + t;          // this wave's compute tile

        // ---- issue next-tile global loads (sh half stages tile sh*8+t+1) ----
        int4 kn, vn;
        if (t < 7) {
            const int row = (sh * 8 + t + 1) * 64 + sr;
            kn = *reinterpret_cast<const int4*>(&Kh[row * 32 + sc]);
            vn = *reinterpret_cast<const int4*>(&Vh[row * 32 + sc]);
        }

        // ---- adj loads (coalesced gathered layout) ----
        unsigned int a4[8];
#pragma unroll
        for (int i = 0; i < 8; ++i)
            a4[i] = adjT[tt * 512 + i * 64 + lane];

        const short* KsC = KsB + (cur * 2 + kh) * 2432;
        const short* VtC = VtB + (cur * 2 + kh) * 2368;

        // ---- QK^T from LDS K frags: S^T[k][q] ----
        f32x16 s[2];
#pragma unroll
        for (int ks = 0; ks < 2; ++ks) {
            union { short4 h4[2]; bf16x8 v; } kfa, kfb;
            const int rowb = (ks * 32 + l5) * 38;
            kfa.h4[0] = *reinterpret_cast<const short4*>(&KsC[rowb + h32 * 8]);
            kfa.h4[1] = *reinterpret_cast<const short4*>(&KsC[rowb + h32 * 8 + 4]);
            kfb.h4[0] = *reinterpret_cast<const short4*>(&KsC[rowb + 16 + h32 * 8]);
            kfb.h4[1] = *reinterpret_cast<const short4*>(&KsC[rowb + 16 + h32 * 8 + 4]);
            s[ks] = MFMA32(kfa.v, qf0, zero16);
            s[ks] = MFMA32(kfb.v, qf1, s[ks]);
        }

        // ---- tile max over raw scores ----
        float tm = s[0][0];
#pragma unroll
        for (int ks = 0; ks < 2; ++ks)
#pragma unroll
            for (int r = ks ? 0 : 1; r < 16; r += 2) {
                const int r1 = (r + 1 < 16) ? r + 1 : r;
                tm = fmaxf(fmaxf(s[ks][r], s[ks][r1]), tm);
            }
        tm = fmaxf(tm, __shfl_xor(tm, 32));

        const float m2n = fmaxf(m2, tm * c1);
        const float resc = exp2f_fast(m2 - m2n);
        m2 = m2n;
        const float negm2 = -m2;

        // ---- p = exp2(s*c1 - m2) * E[adj]; pack bf16 pairs ----
        unsigned int pw[2][8];
        float lsum = 0.f;
#pragma unroll
        for (int ks = 0; ks < 2; ++ks) {
#pragma unroll
            for (int rg = 0; rg < 4; ++rg) {
                const unsigned int aw4 = a4[ks * 4 + rg] << 2;
                float pv[4];
#pragma unroll
                for (int j = 0; j < 4; ++j) {
                    const float Ev = *reinterpret_cast<const float*>(
                        reinterpret_cast<const char*>(&Etab[0]) +
                        ((aw4 >> (8 * j)) & 0x3FCu));
                    const float pe = exp2f_fast(fmaf(s[ks][rg * 4 + j], c1, negm2));
                    const float pp = pe * Ev;
                    pv[j] = pp;
                    lsum += pp;
                }
                pw[ks][rg * 2 + 0] = cvtpk(pv[0], pv[1]);
                pw[ks][rg * 2 + 1] = cvtpk(pv[2], pv[3]);
            }
        }
        lsum += __shfl_xor(lsum, 32);
        l_run = l_run * resc + lsum;

#pragma unroll
        for (int r = 0; r < 16; ++r) o[r] *= resc;

        // ---- PV: O^T += V^T . P^T  (verified shfl exchange) ----
#pragma unroll
        for (int kc = 0; kc < 4; ++kc) {
            const int ks = kc >> 1, half = kc & 1;
            const unsigned int A0 = pw[ks][4 * half + 0], A1 = pw[ks][4 * half + 1];
            const unsigned int B0 = pw[ks][4 * half + 2], B1 = pw[ks][4 * half + 3];
            const unsigned int send0 = h32 ? A0 : B0, send1 = h32 ? A1 : B1;
            const unsigned int rv0 = __shfl_xor(send0, 32);
            const unsigned int rv1 = __shfl_xor(send1, 32);
            const unsigned int own0 = h32 ? B0 : A0, own1 = h32 ? B1 : A1;
            union { unsigned int u[4]; bf16x8 v; } P;
            P.u[0] = h32 ? rv0 : own0;
            P.u[1] = h32 ? rv1 : own1;
            P.u[2] = h32 ? own0 : rv0;
            P.u[3] = h32 ? own1 : rv1;
            bf16x8 vf = *reinterpret_cast<const bf16x8*>(
                &VtC[l5 * 74 + kc * 16 + h32 * 8]);
            o = MFMA32(vf, P.v, o);
        }

        // ---- write next tile into other buffer; one barrier per iter ----
        if (t < 7) {
            short* kd = KsB + ((cur ^ 1) * 2 + sh) * 2432 + sr * 38 + sc;
            *reinterpret_cast<short4*>(kd)     = *reinterpret_cast<short4*>(&kn);
            *reinterpret_cast<short4*>(kd + 4) = *(reinterpret_cast<short4*>(&kn) + 1);
            short* vd = VtB + ((cur ^ 1) * 2 + sh) * 2368;
            const short* vs = reinterpret_cast<const short*>(&vn);
#pragma unroll
            for (int i = 0; i < 8; ++i) vd[(sc + i) * 74 + sr] = vs[i];
        }
        __syncthreads();
    }

    // ---- 2-way split-k flash merge: kh=1 waves post (m,l,o) via LDS ----
    float* scr = reinterpret_cast<float*>(LDSBUF);   // qw*1152 + lane*18
    if (kh == 1) {
        float* myb = scr + qw * 1152 + lane * 18;
        myb[0] = m2;
        myb[1] = l_run;
#pragma unroll
        for (int r = 0; r < 16; ++r) myb[2 + r] = o[r];
    }
    __syncthreads();

    if (kh == 0) {
        const float* pb = scr + qw * 1152 + lane * 18;
        const float m1 = pb[0], l1 = pb[1];
        const float mM = fmaxf(m2, m1);
        const float a0 = exp2f_fast(m2 - mM), a1 = exp2f_fast(m1 - mM);
        const float lM = l_run * a0 + l1 * a1;
        const float inv = 1.0f / lM;
        short* dst = &AO[((size_t)(b * 1024 + q)) * 256 + h * 32];
#pragma unroll
        for (int rg = 0; rg < 4; ++rg) {
            short4 s4;
            s4.x = f2s((o[rg * 4 + 0] * a0 + pb[2 + rg * 4 + 0] * a1) * inv);
            s4.y = f2s((o[rg * 4 + 1] * a0 + pb[2 + rg * 4 + 1] * a1) * inv);
            s4.z = f2s((o[rg * 4 + 2] * a0 + pb[2 + rg * 4 + 2] * a1) * inv);
            s4.w = f2s((o[rg * 4 + 3] * a0 + pb[2 + rg * 4 + 3] * a1) * inv);
            *reinterpret_cast<short4*>(&dst[rg * 8 + h32 * 4]) = s4;
        }
    }
}

// ---------------------------------------------------------------------------
// Kernel 3: output projection (unchanged, verified).
// ---------------------------------------------------------------------------
__global__ __launch_bounds__(256)
void out_gemm(const short* __restrict__ AO, const float* __restrict__ Wo,
              const float* __restrict__ bo, float* __restrict__ out)
{
    __shared__ short As[128 * 72];
    __shared__ short Bs[64 * 72];

    const int tid = threadIdx.x, lane = tid & 63, wid = tid >> 6;
    const int wr = wid >> 1, wcn = wid & 1;
    const int g = lane >> 4, li = lane & 15;
    const int m0 = blockIdx.x * 128, n0 = blockIdx.y * 64;

    f32x4 acc[4][2] = {};
    const int ar = tid >> 3, ac8 = (tid & 7) * 8;
    const int br = tid >> 4, bc4 = (tid & 15) * 4;

    for (int k0 = 0; k0 < 256; k0 += 64) {
        __syncthreads();
#pragma unroll
        for (int it = 0; it < 4; ++it) {
            int row = ar + it * 32;
            *reinterpret_cast<int4*>(&As[row * 72 + ac8]) =
                *reinterpret_cast<const int4*>(&AO[(m0 + row) * 256 + k0 + ac8]);
        }
#pragma unroll
        for (int it = 0; it < 4; ++it) {
            int row = br + it * 16;
            float4 v = *reinterpret_cast<const float4*>(&Wo[(n0 + row) * 256 + k0 + bc4]);
            short4 s4; s4.x = f2s(v.x); s4.y = f2s(v.y); s4.z = f2s(v.z); s4.w = f2s(v.w);
            *reinterpret_cast<short4*>(&Bs[row * 72 + bc4]) = s4;
        }
        __syncthreads();
#pragma unroll
        for (int ks = 0; ks < 2; ++ks) {
            const int kb = ks * 32 + g * 8;
            bf16x8 a[4], bb[2];
#pragma unroll
            for (int i = 0; i < 4; ++i)
                a[i] = *reinterpret_cast<const bf16x8*>(&As[(wr * 64 + i * 16 + li) * 72 + kb]);
#pragma unroll
            for (int j = 0; j < 2; ++j)
                bb[j] = *reinterpret_cast<const bf16x8*>(&Bs[(wcn * 32 + j * 16 + li) * 72 + kb]);
#pragma unroll
            for (int i = 0; i < 4; ++i)
#pragma unroll
                for (int j = 0; j < 2; ++j)
                    acc[i][j] = MFMA16(a[i], bb[j], acc[i][j]);
        }
    }
#pragma unroll
    for (int j = 0; j < 2; ++j) {
        const int col = n0 + wcn * 32 + j * 16 + li;
        const float bv_ = bo[col];
#pragma unroll
        for (int i = 0; i < 4; ++i)
#pragma unroll
            for (int r = 0; r < 4; ++r) {
                const int row = m0 + wr * 64 + i * 16 + g * 4 + r;
                out[row * 256 + col] = acc[i][j][r] + bv_;
            }
    }
}

extern "C" void kernel_launch(void* const* d_in, const int* in_sizes, int n_in,
                              void* d_out, int out_size, void* d_ws, size_t ws_size,
                              hipStream_t stream)
{
    const float* x  = (const float*)d_in[0];
    const int*   adj = (const int*)d_in[1];
    const float* Wq = (const float*)d_in[2];
    const float* bq = (const float*)d_in[3];
    const float* Wk = (const float*)d_in[4];
    const float* bk = (const float*)d_in[5];
    const float* Wv = (const float*)d_in[6];
    const float* bv = (const float*)d_in[7];
    const float* Wo = (const float*)d_in[8];
    const float* bo = (const float*)d_in[9];
    const float* ee = (const float*)d_in[10];
    float* out = (float*)d_out;

    // Workspace: Qb/Kb/Vb [64][1024][32] bf16 (4MB each), AO [8192][256] bf16 (4MB),
    // adjG [8][32][16][8][64] u32 (8MB)  -> 24MB total (known-good budget)
    short* Qb = (short*)d_ws;
    short* Kb = Qb + 2 * 1024 * 1024;
    short* Vb = Kb + 2 * 1024 * 1024;
    short* AO = Vb + 2 * 1024 * 1024;
    unsigned int* adjG = (unsigned int*)(AO + 2 * 1024 * 1024);

    adj_gather<<<dim3(32, 8, 4), 256, 0, stream>>>(adj, adjG);
    qkv_gemm<<<dim3(64, 12), 256, 0, stream>>>(x, Wq, bq, Wk, bk, Wv, bv, Qb, Kb, Vb);
    attn5<<<dim3(8, 64), 512, 0, stream>>>(Qb, Kb, Vb, adjG, ee, AO);
    out_gemm<<<dim3(64, 4), 256, 0, stream>>>(AO, Wo, bo, out);
}

// Round 10
// 87.229 us; speedup vs baseline: 1.0821x; 1.0821x over previous
//
#include <hip/hip_runtime.h>
#include <hip/hip_bf16.h>

typedef float f32x4 __attribute__((ext_vector_type(4)));
typedef float f32x16 __attribute__((ext_vector_type(16)));
typedef __bf16 bf16x8 __attribute__((ext_vector_type(8)));

#define MFMA16(a, b, c) __builtin_amdgcn_mfma_f32_16x16x32_bf16((a), (b), (c), 0, 0, 0)
#define MFMA32(a, b, c) __builtin_amdgcn_mfma_f32_32x32x16_bf16((a), (b), (c), 0, 0, 0)

static __device__ __forceinline__ short f2s(float f) {
    __hip_bfloat16 h = __float2bfloat16(f);
    return *reinterpret_cast<short*>(&h);
}
static __device__ __forceinline__ unsigned int cvtpk(float lo, float hi) {
    unsigned int r;
    asm("v_cvt_pk_bf16_f32 %0, %1, %2" : "=v"(r) : "v"(lo), "v"(hi));
    return r;
}
static __device__ __forceinline__ float exp2f_fast(float x) {
#if __has_builtin(__builtin_amdgcn_exp2f)
    return __builtin_amdgcn_exp2f(x);
#else
    return exp2f(x);
#endif
}

// ---------------------------------------------------------------------------
// Kernel 0: gather adj int32 -> u8 codes in wave order (verified round 8/9).
// adjG[((b*32+qt)*16 + t)*512 + i*64 + lane] holds codes for
//   q = qt*32 + (lane&31), k = t*64 + (i>>2)*32 + (i&3)*8 + (lane>>5)*4 + {0..3}
// ---------------------------------------------------------------------------
__global__ __launch_bounds__(256)
void adj_gather(const int* __restrict__ adj, unsigned int* __restrict__ adjG)
{
    const int tid = threadIdx.x;
    const int qt = blockIdx.x;            // 0..31
    const int b  = blockIdx.y;            // 0..7
    const int j0 = blockIdx.z * 8;        // q-row chunk

    const int4* base = reinterpret_cast<const int4*>(
        adj + ((size_t)(b * 1024 + qt * 32)) * 1024);
    unsigned int* outT = adjG + ((size_t)(b * 32 + qt)) * 16 * 512;

    const int t = tid >> 4;
    const int i = (tid >> 1) & 7;
    const int laneb = 32 * (tid & 1);

#pragma unroll
    for (int jj = 0; jj < 8; ++jj) {
        const int j = j0 + jj;
        const int4 c = base[j * 256 + tid];
        const unsigned int packed =
            (unsigned)c.x | ((unsigned)c.y << 8) | ((unsigned)c.z << 16) | ((unsigned)c.w << 24);
        outT[t * 512 + i * 64 + (j + laneb)] = packed;
    }
}

// ---------------------------------------------------------------------------
// Kernel 1: QKV projection (unchanged, verified).
// ---------------------------------------------------------------------------
__global__ __launch_bounds__(256)
void qkv_gemm(const float* __restrict__ x,
              const float* __restrict__ Wq, const float* __restrict__ bq,
              const float* __restrict__ Wk, const float* __restrict__ bk,
              const float* __restrict__ Wv, const float* __restrict__ bv,
              short* __restrict__ Qb, short* __restrict__ Kb, short* __restrict__ Vb)
{
    __shared__ short As[128 * 72];
    __shared__ short Bs[64 * 72];

    const int tid = threadIdx.x;
    const int lane = tid & 63;
    const int wid = tid >> 6;
    const int wr = wid >> 1, wc = wid & 1;
    const int g = lane >> 4, li = lane & 15;

    const int m0 = blockIdx.x * 128;
    const int gc0 = blockIdx.y * 64;
    const int mat = gc0 >> 8;
    const float* W    = (mat == 0) ? Wq : (mat == 1) ? Wk : Wv;
    const float* bias = (mat == 0) ? bq : (mat == 1) ? bk : bv;
    short* Out        = (mat == 0) ? Qb : (mat == 1) ? Kb : Vb;
    const int wc0 = gc0 & 255;

    f32x4 acc[4][2] = {};

    const int sr = tid >> 4;
    const int sc4 = (tid & 15) * 4;

    for (int k0 = 0; k0 < 256; k0 += 64) {
        __syncthreads();
#pragma unroll
        for (int it = 0; it < 8; ++it) {
            int row = sr + it * 16;
            float4 v = *reinterpret_cast<const float4*>(&x[(m0 + row) * 256 + k0 + sc4]);
            short4 s4;
            s4.x = f2s(v.x); s4.y = f2s(v.y); s4.z = f2s(v.z); s4.w = f2s(v.w);
            *reinterpret_cast<short4*>(&As[row * 72 + sc4]) = s4;
        }
#pragma unroll
        for (int it = 0; it < 4; ++it) {
            int row = sr + it * 16;
            float4 v = *reinterpret_cast<const float4*>(&W[(wc0 + row) * 256 + k0 + sc4]);
            short4 s4;
            s4.x = f2s(v.x); s4.y = f2s(v.y); s4.z = f2s(v.z); s4.w = f2s(v.w);
            *reinterpret_cast<short4*>(&Bs[row * 72 + sc4]) = s4;
        }
        __syncthreads();
#pragma unroll
        for (int ks = 0; ks < 2; ++ks) {
            const int kb = ks * 32 + g * 8;
            bf16x8 a[4], bfr[2];
#pragma unroll
            for (int i = 0; i < 4; ++i)
                a[i] = *reinterpret_cast<const bf16x8*>(&As[(wr * 64 + i * 16 + li) * 72 + kb]);
#pragma unroll
            for (int j = 0; j < 2; ++j)
                bfr[j] = *reinterpret_cast<const bf16x8*>(&Bs[(wc * 32 + j * 16 + li) * 72 + kb]);
#pragma unroll
            for (int i = 0; i < 4; ++i)
#pragma unroll
                for (int j = 0; j < 2; ++j)
                    acc[i][j] = MFMA16(a[i], bfr[j], acc[i][j]);
        }
    }

#pragma unroll
    for (int j = 0; j < 2; ++j) {
        const int colW = wc0 + wc * 32 + j * 16 + li;
        const int h = colW >> 5, d = colW & 31;
        const float bv_ = bias[colW];
#pragma unroll
        for (int i = 0; i < 4; ++i) {
#pragma unroll
            for (int r = 0; r < 4; ++r) {
                const int row = m0 + wr * 64 + i * 16 + g * 4 + r;
                const int bb = row >> 10, nq = row & 1023;
                Out[((bb * 8 + h) * 1024 + nq) * 32 + d] = f2s(acc[i][j][r] + bv_);
            }
        }
    }
}

// ---------------------------------------------------------------------------
// Kernel 2: edge-biased flash attention — attn4 structure (4 waves, shared
// staging, verified @41.6us) widened to 2 k-tiles (128 k) per iteration:
// joint max / single rescale per 128k, half the barriers, conflict-free
// LDS strides 38/74 (attn5-proven).  All math verbatim from verified rounds.
// ---------------------------------------------------------------------------
__global__ __launch_bounds__(256)
void attn6(const short* __restrict__ Qb, const short* __restrict__ Kb,
           const short* __restrict__ Vb, const unsigned int* __restrict__ adjG,
           const float* __restrict__ edge_emb, short* __restrict__ AO)
{
    __shared__ __align__(16) short Ks[2][2][64 * 38];   // [buf][sub] 19456 B
    __shared__ __align__(16) short Vt[2][2][32 * 74];   // [buf][sub] 18944 B
    __shared__ float Etab[8];

    const int tid = threadIdx.x, lane = tid & 63, wid = tid >> 6;
    const int l5 = lane & 31, h32 = lane >> 5;

    // bijective chunked XCD swizzle (512 blocks = 8 XCD x 64)
    const int orig = blockIdx.x + blockIdx.y * 8;
    const int flat = (orig & 7) * 64 + (orig >> 3);
    const int qb = flat & 7, bh = flat >> 3;
    const int b = bh >> 3, h = bh & 7;
    const int qt = qb * 4 + wid;
    const int q  = qt * 32 + l5;

    const short* Qh = Qb + bh * (1024 * 32);
    const short* Kh = Kb + bh * (1024 * 32);
    const short* Vh = Vb + bh * (1024 * 32);
    const unsigned int* adjT = adjG + ((size_t)(b * 32 + qt)) * 16 * 512;

    if (tid < 5) Etab[tid] = __expf(edge_emb[tid * 8 + h]);

    const bf16x8 qf0 = *reinterpret_cast<const bf16x8*>(&Qh[q * 32 + h32 * 8]);
    const bf16x8 qf1 = *reinterpret_cast<const bf16x8*>(&Qh[q * 32 + 16 + h32 * 8]);

    const float c1 = 0.25503486f;   // log2(e)/sqrt(32)
    const f32x16 zero16 = {};

    f32x16 o = {};
    float m2 = -1e30f, l_run = 0.f;

    // staging map (verified attn4): sr = tid>>2 (k-row), sc = (tid&3)*8
    const int sr = tid >> 2;
    const int sc = (tid & 3) * 8;

    // prologue: stage k-pair 0 (subs 0,1) into buf 0
#pragma unroll
    for (int u = 0; u < 2; ++u) {
        const int row = u * 64 + sr;
        int4 kr = *reinterpret_cast<const int4*>(&Kh[row * 32 + sc]);
        int4 vr = *reinterpret_cast<const int4*>(&Vh[row * 32 + sc]);
        short* kd = &Ks[0][u][sr * 38 + sc];
        *reinterpret_cast<short4*>(kd)     = *reinterpret_cast<short4*>(&kr);
        *reinterpret_cast<short4*>(kd + 4) = *(reinterpret_cast<short4*>(&kr) + 1);
        const short* vs = reinterpret_cast<const short*>(&vr);
#pragma unroll
        for (int i = 0; i < 8; ++i) Vt[0][u][(sc + i) * 74 + sr] = vs[i];
    }
    __syncthreads();

    for (int t = 0; t < 8; ++t) {
        const int cur = t & 1;

        // ---- issue next-pair global loads (hidden under compute) ----
        int4 kn[2], vn[2];
        if (t < 7) {
#pragma unroll
            for (int u = 0; u < 2; ++u) {
                const int row = (t + 1) * 128 + u * 64 + sr;
                kn[u] = *reinterpret_cast<const int4*>(&Kh[row * 32 + sc]);
                vn[u] = *reinterpret_cast<const int4*>(&Vh[row * 32 + sc]);
            }
        }

        // ---- adj loads for both tiles of the pair ----
        unsigned int a4[2][8];
#pragma unroll
        for (int u = 0; u < 2; ++u)
#pragma unroll
            for (int i = 0; i < 8; ++i)
                a4[u][i] = adjT[(2 * t + u) * 512 + i * 64 + lane];

        // ---- QK^T for both subs: S^T[k][q] ----
        f32x16 s[2][2];
#pragma unroll
        for (int u = 0; u < 2; ++u)
#pragma unroll
            for (int ks = 0; ks < 2; ++ks) {
                union { short4 h4[2]; bf16x8 v; } kfa, kfb;
                const int rowb = (ks * 32 + l5) * 38;
                const short* KsC = &Ks[cur][u][0];
                kfa.h4[0] = *reinterpret_cast<const short4*>(&KsC[rowb + h32 * 8]);
                kfa.h4[1] = *reinterpret_cast<const short4*>(&KsC[rowb + h32 * 8 + 4]);
                kfb.h4[0] = *reinterpret_cast<const short4*>(&KsC[rowb + 16 + h32 * 8]);
                kfb.h4[1] = *reinterpret_cast<const short4*>(&KsC[rowb + 16 + h32 * 8 + 4]);
                s[u][ks] = MFMA32(kfa.v, qf0, zero16);
                s[u][ks] = MFMA32(kfb.v, qf1, s[u][ks]);
            }

        // ---- joint tile max over 128 raw scores ----
        float tm = s[0][0][0];
#pragma unroll
        for (int u = 0; u < 2; ++u)
#pragma unroll
            for (int ks = 0; ks < 2; ++ks)
#pragma unroll
                for (int r = (u || ks) ? 0 : 1; r < 16; r += 2) {
                    const int r1 = (r + 1 < 16) ? r + 1 : r;
                    tm = fmaxf(fmaxf(s[u][ks][r], s[u][ks][r1]), tm);
                }
        tm = fmaxf(tm, __shfl_xor(tm, 32));

        const float m2n = fmaxf(m2, tm * c1);
        const float resc = exp2f_fast(m2 - m2n);
        m2 = m2n;
        const float negm2 = -m2;

        // ---- p = exp2(s*c1 - m2) * E[adj]; pack bf16 pairs ----
        unsigned int pw[2][2][8];
        float lsum = 0.f;
#pragma unroll
        for (int u = 0; u < 2; ++u)
#pragma unroll
            for (int ks = 0; ks < 2; ++ks) {
#pragma unroll
                for (int rg = 0; rg < 4; ++rg) {
                    const unsigned int aw4 = a4[u][ks * 4 + rg] << 2;
                    float pv[4];
#pragma unroll
                    for (int j = 0; j < 4; ++j) {
                        const float Ev = *reinterpret_cast<const float*>(
                            reinterpret_cast<const char*>(&Etab[0]) +
                            ((aw4 >> (8 * j)) & 0x3FCu));
                        const float pe = exp2f_fast(fmaf(s[u][ks][rg * 4 + j], c1, negm2));
                        const float pp = pe * Ev;
                        pv[j] = pp;
                        lsum += pp;
                    }
                    pw[u][ks][rg * 2 + 0] = cvtpk(pv[0], pv[1]);
                    pw[u][ks][rg * 2 + 1] = cvtpk(pv[2], pv[3]);
                }
            }
        lsum += __shfl_xor(lsum, 32);
        l_run = l_run * resc + lsum;

#pragma unroll
        for (int r = 0; r < 16; ++r) o[r] *= resc;

        // ---- PV over both subs: O^T += V^T . P^T ----
#pragma unroll
        for (int u = 0; u < 2; ++u)
#pragma unroll
            for (int kc = 0; kc < 4; ++kc) {
                const int ks = kc >> 1, half = kc & 1;
                const unsigned int A0 = pw[u][ks][4 * half + 0], A1 = pw[u][ks][4 * half + 1];
                const unsigned int B0 = pw[u][ks][4 * half + 2], B1 = pw[u][ks][4 * half + 3];
                const unsigned int send0 = h32 ? A0 : B0, send1 = h32 ? A1 : B1;
                const unsigned int rv0 = __shfl_xor(send0, 32);
                const unsigned int rv1 = __shfl_xor(send1, 32);
                const unsigned int own0 = h32 ? B0 : A0, own1 = h32 ? B1 : A1;
                union { unsigned int uu[4]; bf16x8 v; } P;
                P.uu[0] = h32 ? rv0 : own0;
                P.uu[1] = h32 ? rv1 : own1;
                P.uu[2] = h32 ? own0 : rv0;
                P.uu[3] = h32 ? own1 : rv1;
                bf16x8 vf = *reinterpret_cast<const bf16x8*>(
                    &Vt[cur][u][l5 * 74 + kc * 16 + h32 * 8]);
                o = MFMA32(vf, P.v, o);
            }

        // ---- write next pair into other buffer; one barrier per pair ----
        if (t < 7) {
#pragma unroll
            for (int u = 0; u < 2; ++u) {
                short* kd = &Ks[cur ^ 1][u][sr * 38 + sc];
                *reinterpret_cast<short4*>(kd)     = *reinterpret_cast<short4*>(&kn[u]);
                *reinterpret_cast<short4*>(kd + 4) = *(reinterpret_cast<short4*>(&kn[u]) + 1);
                const short* vs = reinterpret_cast<const short*>(&vn[u]);
#pragma unroll
                for (int i = 0; i < 8; ++i) Vt[cur ^ 1][u][(sc + i) * 74 + sr] = vs[i];
            }
            __syncthreads();
        }
    }

    // ---- epilogue: every wave writes its own q-tile ----
    const float inv = 1.0f / l_run;
    short* dst = &AO[((size_t)(b * 1024 + q)) * 256 + h * 32];
#pragma unroll
    for (int rg = 0; rg < 4; ++rg) {
        short4 s4;
        s4.x = f2s(o[rg * 4 + 0] * inv);
        s4.y = f2s(o[rg * 4 + 1] * inv);
        s4.z = f2s(o[rg * 4 + 2] * inv);
        s4.w = f2s(o[rg * 4 + 3] * inv);
        *reinterpret_cast<short4*>(&dst[rg * 8 + h32 * 4]) = s4;
    }
}

// ---------------------------------------------------------------------------
// Kernel 3: output projection (unchanged, verified).
// ---------------------------------------------------------------------------
__global__ __launch_bounds__(256)
void out_gemm(const short* __restrict__ AO, const float* __restrict__ Wo,
              const float* __restrict__ bo, float* __restrict__ out)
{
    __shared__ short As[128 * 72];
    __shared__ short Bs[64 * 72];

    const int tid = threadIdx.x, lane = tid & 63, wid = tid >> 6;
    const int wr = wid >> 1, wcn = wid & 1;
    const int g = lane >> 4, li = lane & 15;
    const int m0 = blockIdx.x * 128, n0 = blockIdx.y * 64;

    f32x4 acc[4][2] = {};
    const int ar = tid >> 3, ac8 = (tid & 7) * 8;
    const int br = tid >> 4, bc4 = (tid & 15) * 4;

    for (int k0 = 0; k0 < 256; k0 += 64) {
        __syncthreads();
#pragma unroll
        for (int it = 0; it < 4; ++it) {
            int row = ar + it * 32;
            *reinterpret_cast<int4*>(&As[row * 72 + ac8]) =
                *reinterpret_cast<const int4*>(&AO[(m0 + row) * 256 + k0 + ac8]);
        }
#pragma unroll
        for (int it = 0; it < 4; ++it) {
            int row = br + it * 16;
            float4 v = *reinterpret_cast<const float4*>(&Wo[(n0 + row) * 256 + k0 + bc4]);
            short4 s4; s4.x = f2s(v.x); s4.y = f2s(v.y); s4.z = f2s(v.z); s4.w = f2s(v.w);
            *reinterpret_cast<short4*>(&Bs[row * 72 + bc4]) = s4;
        }
        __syncthreads();
#pragma unroll
        for (int ks = 0; ks < 2; ++ks) {
            const int kb = ks * 32 + g * 8;
            bf16x8 a[4], bb[2];
#pragma unroll
            for (int i = 0; i < 4; ++i)
                a[i] = *reinterpret_cast<const bf16x8*>(&As[(wr * 64 + i * 16 + li) * 72 + kb]);
#pragma unroll
            for (int j = 0; j < 2; ++j)
                bb[j] = *reinterpret_cast<const bf16x8*>(&Bs[(wcn * 32 + j * 16 + li) * 72 + kb]);
#pragma unroll
            for (int i = 0; i < 4; ++i)
#pragma unroll
                for (int j = 0; j < 2; ++j)
                    acc[i][j] = MFMA16(a[i], bb[j], acc[i][j]);
        }
    }
#pragma unroll
    for (int j = 0; j < 2; ++j) {
        const int col = n0 + wcn * 32 + j * 16 + li;
        const float bv_ = bo[col];
#pragma unroll
        for (int i = 0; i < 4; ++i)
#pragma unroll
            for (int r = 0; r < 4; ++r) {
                const int row = m0 + wr * 64 + i * 16 + g * 4 + r;
                out[row * 256 + col] = acc[i][j][r] + bv_;
            }
    }
}

extern "C" void kernel_launch(void* const* d_in, const int* in_sizes, int n_in,
                              void* d_out, int out_size, void* d_ws, size_t ws_size,
                              hipStream_t stream)
{
    const float* x  = (const float*)d_in[0];
    const int*   adj = (const int*)d_in[1];
    const float* Wq = (const float*)d_in[2];
    const float* bq = (const float*)d_in[3];
    const float* Wk = (const float*)d_in[4];
    const float* bk = (const float*)d_in[5];
    const float* Wv = (const float*)d_in[6];
    const float* bv = (const float*)d_in[7];
    const float* Wo = (const float*)d_in[8];
    const float* bo = (const float*)d_in[9];
    const float* ee = (const float*)d_in[10];
    float* out = (float*)d_out;

    // Workspace: Qb/Kb/Vb [64][1024][32] bf16 (4MB each), AO [8192][256] bf16 (4MB),
    // adjG [8][32][16][8][64] u32 (8MB)  -> 24MB total (known-good budget)
    short* Qb = (short*)d_ws;
    short* Kb = Qb + 2 * 1024 * 1024;
    short* Vb = Kb + 2 * 1024 * 1024;
    short* AO = Vb + 2 * 1024 * 1024;
    unsigned int* adjG = (unsigned int*)(AO + 2 * 1024 * 1024);

    adj_gather<<<dim3(32, 8, 4), 256, 0, stream>>>(adj, adjG);
    qkv_gemm<<<dim3(64, 12), 256, 0, stream>>>(x, Wq, bq, Wk, bk, Wv, bv, Qb, Kb, Vb);
    attn6<<<dim3(8, 64), 256, 0, stream>>>(Qb, Kb, Vb, adjG, ee, AO);
    out_gemm<<<dim3(64, 4), 256, 0, stream>>>(AO, Wo, bo, out);
}

// Round 11
// 68.058 us; speedup vs baseline: 1.3869x; 1.2817x over previous
//
#include <hip/hip_runtime.h>
#include <hip/hip_bf16.h>

typedef float f32x4 __attribute__((ext_vector_type(4)));
typedef float f32x16 __attribute__((ext_vector_type(16)));
typedef __bf16 bf16x8 __attribute__((ext_vector_type(8)));

#define MFMA16(a, b, c) __builtin_amdgcn_mfma_f32_16x16x32_bf16((a), (b), (c), 0, 0, 0)
#define MFMA32(a, b, c) __builtin_amdgcn_mfma_f32_32x32x16_bf16((a), (b), (c), 0, 0, 0)

static __device__ __forceinline__ short f2s(float f) {
    __hip_bfloat16 h = __float2bfloat16(f);
    return *reinterpret_cast<short*>(&h);
}
static __device__ __forceinline__ unsigned int cvtpk(float lo, float hi) {
    unsigned int r;
    asm("v_cvt_pk_bf16_f32 %0, %1, %2" : "=v"(r) : "v"(lo), "v"(hi));
    return r;
}
static __device__ __forceinline__ float exp2f_fast(float x) {
#if __has_builtin(__builtin_amdgcn_exp2f)
    return __builtin_amdgcn_exp2f(x);
#else
    return exp2f(x);
#endif
}

// ---------------------------------------------------------------------------
// Kernel A (fused front): blocks [0,768) = QKV projection (verified body);
// blocks [768,1792) = adj gather (verified body).  Independent work — the
// memory-bound gather overlaps the compute-bound GEMM instead of serializing.
// ---------------------------------------------------------------------------
__global__ __launch_bounds__(256)
void qkv_and_gather(const float* __restrict__ x,
                    const float* __restrict__ Wq, const float* __restrict__ bq,
                    const float* __restrict__ Wk, const float* __restrict__ bk,
                    const float* __restrict__ Wv, const float* __restrict__ bv,
                    short* __restrict__ Qb, short* __restrict__ Kb, short* __restrict__ Vb,
                    const int* __restrict__ adj, unsigned int* __restrict__ adjG)
{
    __shared__ short As[128 * 72];
    __shared__ short Bs[64 * 72];

    const int bx = blockIdx.x;
    const int tid = threadIdx.x;

    if (bx < 768) {
        // ---------------- QKV GEMM body (verbatim, verified) ----------------
        const int lane = tid & 63;
        const int wid = tid >> 6;
        const int wr = wid >> 1, wc = wid & 1;
        const int g = lane >> 4, li = lane & 15;

        const int m0 = (bx & 63) * 128;
        const int gc0 = (bx >> 6) * 64;
        const int mat = gc0 >> 8;
        const float* W    = (mat == 0) ? Wq : (mat == 1) ? Wk : Wv;
        const float* bias = (mat == 0) ? bq : (mat == 1) ? bk : bv;
        short* Out        = (mat == 0) ? Qb : (mat == 1) ? Kb : Vb;
        const int wc0 = gc0 & 255;

        f32x4 acc[4][2] = {};

        const int sr = tid >> 4;
        const int sc4 = (tid & 15) * 4;

        for (int k0 = 0; k0 < 256; k0 += 64) {
            __syncthreads();
#pragma unroll
            for (int it = 0; it < 8; ++it) {
                int row = sr + it * 16;
                float4 v = *reinterpret_cast<const float4*>(&x[(m0 + row) * 256 + k0 + sc4]);
                short4 s4;
                s4.x = f2s(v.x); s4.y = f2s(v.y); s4.z = f2s(v.z); s4.w = f2s(v.w);
                *reinterpret_cast<short4*>(&As[row * 72 + sc4]) = s4;
            }
#pragma unroll
            for (int it = 0; it < 4; ++it) {
                int row = sr + it * 16;
                float4 v = *reinterpret_cast<const float4*>(&W[(wc0 + row) * 256 + k0 + sc4]);
                short4 s4;
                s4.x = f2s(v.x); s4.y = f2s(v.y); s4.z = f2s(v.z); s4.w = f2s(v.w);
                *reinterpret_cast<short4*>(&Bs[row * 72 + sc4]) = s4;
            }
            __syncthreads();
#pragma unroll
            for (int ks = 0; ks < 2; ++ks) {
                const int kb = ks * 32 + g * 8;
                bf16x8 a[4], bfr[2];
#pragma unroll
                for (int i = 0; i < 4; ++i)
                    a[i] = *reinterpret_cast<const bf16x8*>(&As[(wr * 64 + i * 16 + li) * 72 + kb]);
#pragma unroll
                for (int j = 0; j < 2; ++j)
                    bfr[j] = *reinterpret_cast<const bf16x8*>(&Bs[(wc * 32 + j * 16 + li) * 72 + kb]);
#pragma unroll
                for (int i = 0; i < 4; ++i)
#pragma unroll
                    for (int j = 0; j < 2; ++j)
                        acc[i][j] = MFMA16(a[i], bfr[j], acc[i][j]);
            }
        }

#pragma unroll
        for (int j = 0; j < 2; ++j) {
            const int colW = wc0 + wc * 32 + j * 16 + li;
            const int h = colW >> 5, d = colW & 31;
            const float bv_ = bias[colW];
#pragma unroll
            for (int i = 0; i < 4; ++i) {
#pragma unroll
                for (int r = 0; r < 4; ++r) {
                    const int row = m0 + wr * 64 + i * 16 + g * 4 + r;
                    const int bb = row >> 10, nq = row & 1023;
                    Out[((bb * 8 + h) * 1024 + nq) * 32 + d] = f2s(acc[i][j][r] + bv_);
                }
            }
        }
    } else {
        // ---------------- adj gather body (verbatim, verified) ----------------
        const int gx = bx - 768;               // 0..1023
        const int qt = gx & 31;
        const int b  = (gx >> 5) & 7;
        const int j0 = (gx >> 8) * 8;

        const int4* base = reinterpret_cast<const int4*>(
            adj + ((size_t)(b * 1024 + qt * 32)) * 1024);
        unsigned int* outT = adjG + ((size_t)(b * 32 + qt)) * 16 * 512;

        const int t = tid >> 4;
        const int i = (tid >> 1) & 7;
        const int laneb = 32 * (tid & 1);

#pragma unroll
        for (int jj = 0; jj < 8; ++jj) {
            const int j = j0 + jj;
            const int4 c = base[j * 256 + tid];
            const unsigned int packed =
                (unsigned)c.x | ((unsigned)c.y << 8) | ((unsigned)c.z << 16) | ((unsigned)c.w << 24);
            outT[t * 512 + i * 64 + (j + laneb)] = packed;
        }
    }
}

// ---------------------------------------------------------------------------
// Kernel B: edge-biased flash attention — round-8 attn4 structure (verified
// @41.6us) with the ONLY change being conflict-free LDS strides 38/74
// (proven zero-conflict in rounds 9/10 with identical access patterns).
// ---------------------------------------------------------------------------
__global__ __launch_bounds__(256)
void attn4b(const short* __restrict__ Qb, const short* __restrict__ Kb,
            const short* __restrict__ Vb, const unsigned int* __restrict__ adjG,
            const float* __restrict__ edge_emb, short* __restrict__ AO)
{
    __shared__ __align__(16) short Ks[2][64 * 38];   // [row][d], 76B rows
    __shared__ __align__(16) short Vt[2][32 * 74];   // [d][row], 148B rows
    __shared__ float Etab[8];

    const int tid = threadIdx.x, lane = tid & 63, wid = tid >> 6;
    const int l5 = lane & 31, h32 = lane >> 5;

    // bijective chunked XCD swizzle (512 blocks = 8 XCD x 64)
    const int orig = blockIdx.x + blockIdx.y * 8;
    const int flat = (orig & 7) * 64 + (orig >> 3);
    const int qb = flat & 7, bh = flat >> 3;
    const int b = bh >> 3, h = bh & 7;
    const int qt = qb * 4 + wid;         // wave's q-tile (0..31)
    const int q  = qt * 32 + l5;

    const short* Qh = Qb + bh * (1024 * 32);
    const short* Kh = Kb + bh * (1024 * 32);
    const short* Vh = Vb + bh * (1024 * 32);
    const unsigned int* adjT = adjG + ((size_t)(b * 32 + qt)) * 16 * 512;

    if (tid < 5) Etab[tid] = __expf(edge_emb[tid * 8 + h]);

    // Q fragments (B-operand): col=q=l5, k(d) = c*16 + h32*8 + j
    const bf16x8 qf0 = *reinterpret_cast<const bf16x8*>(&Qh[q * 32 + h32 * 8]);
    const bf16x8 qf1 = *reinterpret_cast<const bf16x8*>(&Qh[q * 32 + 16 + h32 * 8]);

    const float c1 = 0.25503486f;   // log2(e)/sqrt(32)
    const f32x16 zero16 = {};

    f32x16 o = {};
    float m2 = -1e30f, l_run = 0.f;

    // staging map: thread -> (row sr = tid>>2, 16B chunk sc = (tid&3)*8 shorts)
    const int sr = tid >> 2;
    const int sc = (tid & 3) * 8;

    // prologue: load + write tile 0 into buffer 0
    {
        int4 kr = *reinterpret_cast<const int4*>(&Kh[sr * 32 + sc]);
        int4 vr = *reinterpret_cast<const int4*>(&Vh[sr * 32 + sc]);
        short* kd = &Ks[0][sr * 38 + sc];
        *reinterpret_cast<short4*>(kd)     = *reinterpret_cast<short4*>(&kr);
        *reinterpret_cast<short4*>(kd + 4) = *(reinterpret_cast<short4*>(&kr) + 1);
        const short* vs = reinterpret_cast<const short*>(&vr);
#pragma unroll
        for (int i = 0; i < 8; ++i) Vt[0][(sc + i) * 74 + sr] = vs[i];
    }
    __syncthreads();

    for (int t = 0; t < 16; ++t) {
        const int cur = t & 1;
        const int k0 = t * 64;

        // ---- issue next-tile global loads (hidden under compute) ----
        int4 kn, vn;
        if (t < 15) {
            kn = *reinterpret_cast<const int4*>(&Kh[(k0 + 64 + sr) * 32 + sc]);
            vn = *reinterpret_cast<const int4*>(&Vh[(k0 + 64 + sr) * 32 + sc]);
        }

        // ---- adj loads (coalesced gathered layout) ----
        unsigned int a4[8];
#pragma unroll
        for (int i = 0; i < 8; ++i)
            a4[i] = adjT[t * 512 + i * 64 + lane];

        // ---- QK^T from LDS K frags: S^T[k][q] ----
        f32x16 s[2];
#pragma unroll
        for (int ks = 0; ks < 2; ++ks) {
            union { short4 h4[2]; bf16x8 v; } kfa, kfb;
            const int rowb = (ks * 32 + l5) * 38;
            kfa.h4[0] = *reinterpret_cast<const short4*>(&Ks[cur][rowb + h32 * 8]);
            kfa.h4[1] = *reinterpret_cast<const short4*>(&Ks[cur][rowb + h32 * 8 + 4]);
            kfb.h4[0] = *reinterpret_cast<const short4*>(&Ks[cur][rowb + 16 + h32 * 8]);
            kfb.h4[1] = *reinterpret_cast<const short4*>(&Ks[cur][rowb + 16 + h32 * 8 + 4]);
            s[ks] = MFMA32(kfa.v, qf0, zero16);
            s[ks] = MFMA32(kfb.v, qf1, s[ks]);
        }

        // ---- tile max over raw scores ----
        float tm = s[0][0];
#pragma unroll
        for (int ks = 0; ks < 2; ++ks)
#pragma unroll
            for (int r = ks ? 0 : 1; r < 16; r += 2) {
                const int r1 = (r + 1 < 16) ? r + 1 : r;
                tm = fmaxf(fmaxf(s[ks][r], s[ks][r1]), tm);
            }
        tm = fmaxf(tm, __shfl_xor(tm, 32));

        const float m2n = fmaxf(m2, tm * c1);
        const float resc = exp2f_fast(m2 - m2n);
        m2 = m2n;
        const float negm2 = -m2;

        // ---- p = exp2(s*c1 - m2) * E[adj]; pack bf16 pairs ----
        unsigned int pw[2][8];
        float lsum = 0.f;
#pragma unroll
        for (int ks = 0; ks < 2; ++ks) {
#pragma unroll
            for (int rg = 0; rg < 4; ++rg) {
                const unsigned int aw4 = a4[ks * 4 + rg] << 2;
                float pv[4];
#pragma unroll
                for (int j = 0; j < 4; ++j) {
                    const float Ev = *reinterpret_cast<const float*>(
                        reinterpret_cast<const char*>(&Etab[0]) +
                        ((aw4 >> (8 * j)) & 0x3FCu));
                    const float pe = exp2f_fast(fmaf(s[ks][rg * 4 + j], c1, negm2));
                    const float pp = pe * Ev;
                    pv[j] = pp;
                    lsum += pp;
                }
                pw[ks][rg * 2 + 0] = cvtpk(pv[0], pv[1]);
                pw[ks][rg * 2 + 1] = cvtpk(pv[2], pv[3]);
            }
        }
        lsum += __shfl_xor(lsum, 32);
        l_run = l_run * resc + lsum;

#pragma unroll
        for (int r = 0; r < 16; ++r) o[r] *= resc;

        // ---- PV: O^T += V^T . P^T  (verified shfl exchange) ----
#pragma unroll
        for (int kc = 0; kc < 4; ++kc) {
            const int ks = kc >> 1, half = kc & 1;
            const unsigned int A0 = pw[ks][4 * half + 0], A1 = pw[ks][4 * half + 1];
            const unsigned int B0 = pw[ks][4 * half + 2], B1 = pw[ks][4 * half + 3];
            const unsigned int send0 = h32 ? A0 : B0, send1 = h32 ? A1 : B1;
            const unsigned int rv0 = __shfl_xor(send0, 32);
            const unsigned int rv1 = __shfl_xor(send1, 32);
            const unsigned int own0 = h32 ? B0 : A0, own1 = h32 ? B1 : A1;
            union { unsigned int u[4]; bf16x8 v; } P;
            P.u[0] = h32 ? rv0 : own0;
            P.u[1] = h32 ? rv1 : own1;
            P.u[2] = h32 ? own0 : rv0;
            P.u[3] = h32 ? own1 : rv1;
            bf16x8 vf = *reinterpret_cast<const bf16x8*>(
                &Vt[cur][l5 * 74 + kc * 16 + h32 * 8]);
            o = MFMA32(vf, P.v, o);
        }

        // ---- write next tile into other buffer; single barrier per iter ----
        if (t < 15) {
            short* kd = &Ks[cur ^ 1][sr * 38 + sc];
            *reinterpret_cast<short4*>(kd)     = *reinterpret_cast<short4*>(&kn);
            *reinterpret_cast<short4*>(kd + 4) = *(reinterpret_cast<short4*>(&kn) + 1);
            const short* vs = reinterpret_cast<const short*>(&vn);
#pragma unroll
            for (int i = 0; i < 8; ++i) Vt[cur ^ 1][(sc + i) * 74 + sr] = vs[i];
            __syncthreads();
        }
    }

    // ---- epilogue: every wave writes its own q-tile (no merge needed) ----
    const float inv = 1.0f / l_run;
    short* dst = &AO[((size_t)(b * 1024 + q)) * 256 + h * 32];
#pragma unroll
    for (int rg = 0; rg < 4; ++rg) {
        short4 s4;
        s4.x = f2s(o[rg * 4 + 0] * inv);
        s4.y = f2s(o[rg * 4 + 1] * inv);
        s4.z = f2s(o[rg * 4 + 2] * inv);
        s4.w = f2s(o[rg * 4 + 3] * inv);
        *reinterpret_cast<short4*>(&dst[rg * 8 + h32 * 4]) = s4;
    }
}

// ---------------------------------------------------------------------------
// Kernel C: output projection (unchanged, verified).
// ---------------------------------------------------------------------------
__global__ __launch_bounds__(256)
void out_gemm(const short* __restrict__ AO, const float* __restrict__ Wo,
              const float* __restrict__ bo, float* __restrict__ out)
{
    __shared__ short As[128 * 72];
    __shared__ short Bs[64 * 72];

    const int tid = threadIdx.x, lane = tid & 63, wid = tid >> 6;
    const int wr = wid >> 1, wcn = wid & 1;
    const int g = lane >> 4, li = lane & 15;
    const int m0 = blockIdx.x * 128, n0 = blockIdx.y * 64;

    f32x4 acc[4][2] = {};
    const int ar = tid >> 3, ac8 = (tid & 7) * 8;
    const int br = tid >> 4, bc4 = (tid & 15) * 4;

    for (int k0 = 0; k0 < 256; k0 += 64) {
        __syncthreads();
#pragma unroll
        for (int it = 0; it < 4; ++it) {
            int row = ar + it * 32;
            *reinterpret_cast<int4*>(&As[row * 72 + ac8]) =
                *reinterpret_cast<const int4*>(&AO[(m0 + row) * 256 + k0 + ac8]);
        }
#pragma unroll
        for (int it = 0; it < 4; ++it) {
            int row = br + it * 16;
            float4 v = *reinterpret_cast<const float4*>(&Wo[(n0 + row) * 256 + k0 + bc4]);
            short4 s4; s4.x = f2s(v.x); s4.y = f2s(v.y); s4.z = f2s(v.z); s4.w = f2s(v.w);
            *reinterpret_cast<short4*>(&Bs[row * 72 + bc4]) = s4;
        }
        __syncthreads();
#pragma unroll
        for (int ks = 0; ks < 2; ++ks) {
            const int kb = ks * 32 + g * 8;
            bf16x8 a[4], bb[2];
#pragma unroll
            for (int i = 0; i < 4; ++i)
                a[i] = *reinterpret_cast<const bf16x8*>(&As[(wr * 64 + i * 16 + li) * 72 + kb]);
#pragma unroll
            for (int j = 0; j < 2; ++j)
                bb[j] = *reinterpret_cast<const bf16x8*>(&Bs[(wcn * 32 + j * 16 + li) * 72 + kb]);
#pragma unroll
            for (int i = 0; i < 4; ++i)
#pragma unroll
                for (int j = 0; j < 2; ++j)
                    acc[i][j] = MFMA16(a[i], bb[j], acc[i][j]);
        }
    }
#pragma unroll
    for (int j = 0; j < 2; ++j) {
        const int col = n0 + wcn * 32 + j * 16 + li;
        const float bv_ = bo[col];
#pragma unroll
        for (int i = 0; i < 4; ++i)
#pragma unroll
            for (int r = 0; r < 4; ++r) {
                const int row = m0 + wr * 64 + i * 16 + g * 4 + r;
                out[row * 256 + col] = acc[i][j][r] + bv_;
            }
    }
}

extern "C" void kernel_launch(void* const* d_in, const int* in_sizes, int n_in,
                              void* d_out, int out_size, void* d_ws, size_t ws_size,
                              hipStream_t stream)
{
    const float* x  = (const float*)d_in[0];
    const int*   adj = (const int*)d_in[1];
    const float* Wq = (const float*)d_in[2];
    const float* bq = (const float*)d_in[3];
    const float* Wk = (const float*)d_in[4];
    const float* bk = (const float*)d_in[5];
    const float* Wv = (const float*)d_in[6];
    const float* bv = (const float*)d_in[7];
    const float* Wo = (const float*)d_in[8];
    const float* bo = (const float*)d_in[9];
    const float* ee = (const float*)d_in[10];
    float* out = (float*)d_out;

    // Workspace: Qb/Kb/Vb [64][1024][32] bf16 (4MB each), AO [8192][256] bf16 (4MB),
    // adjG [8][32][16][8][64] u32 (8MB)  -> 24MB total (known-good budget)
    short* Qb = (short*)d_ws;
    short* Kb = Qb + 2 * 1024 * 1024;
    short* Vb = Kb + 2 * 1024 * 1024;
    short* AO = Vb + 2 * 1024 * 1024;
    unsigned int* adjG = (unsigned int*)(AO + 2 * 1024 * 1024);

    qkv_and_gather<<<1792, 256, 0, stream>>>(x, Wq, bq, Wk, bk, Wv, bv,
                                             Qb, Kb, Vb, adj, adjG);
    attn4b<<<dim3(8, 64), 256, 0, stream>>>(Qb, Kb, Vb, adjG, ee, AO);
    out_gemm<<<dim3(64, 4), 256, 0, stream>>>(AO, Wo, bo, out);
}

// Round 12
// 58.572 us; speedup vs baseline: 1.6115x; 1.1619x over previous
//
#include <hip/hip_runtime.h>
#include <hip/hip_bf16.h>

typedef float f32x4 __attribute__((ext_vector_type(4)));
typedef float f32x16 __attribute__((ext_vector_type(16)));
typedef __bf16 bf16x8 __attribute__((ext_vector_type(8)));

#define MFMA16(a, b, c) __builtin_amdgcn_mfma_f32_16x16x32_bf16((a), (b), (c), 0, 0, 0)
#define MFMA32(a, b, c) __builtin_amdgcn_mfma_f32_32x32x16_bf16((a), (b), (c), 0, 0, 0)

static __device__ __forceinline__ short f2s(float f) {
    __hip_bfloat16 h = __float2bfloat16(f);
    return *reinterpret_cast<short*>(&h);
}
static __device__ __forceinline__ unsigned int cvtpk(float lo, float hi) {
    unsigned int r;
    asm("v_cvt_pk_bf16_f32 %0, %1, %2" : "=v"(r) : "v"(lo), "v"(hi));
    return r;
}
static __device__ __forceinline__ float exp2f_fast(float x) {
#if __has_builtin(__builtin_amdgcn_exp2f)
    return __builtin_amdgcn_exp2f(x);
#else
    return exp2f(x);
#endif
}

// ---------------------------------------------------------------------------
// Kernel A (fused front): blocks [0,768) = QKV projection; [768,1792) = adj
// gather.  Verbatim from round 11 (verified).
// ---------------------------------------------------------------------------
__global__ __launch_bounds__(256)
void qkv_and_gather(const float* __restrict__ x,
                    const float* __restrict__ Wq, const float* __restrict__ bq,
                    const float* __restrict__ Wk, const float* __restrict__ bk,
                    const float* __restrict__ Wv, const float* __restrict__ bv,
                    short* __restrict__ Qb, short* __restrict__ Kb, short* __restrict__ Vb,
                    const int* __restrict__ adj, unsigned int* __restrict__ adjG)
{
    __shared__ short As[128 * 72];
    __shared__ short Bs[64 * 72];

    const int bx = blockIdx.x;
    const int tid = threadIdx.x;

    if (bx < 768) {
        const int lane = tid & 63;
        const int wid = tid >> 6;
        const int wr = wid >> 1, wc = wid & 1;
        const int g = lane >> 4, li = lane & 15;

        const int m0 = (bx & 63) * 128;
        const int gc0 = (bx >> 6) * 64;
        const int mat = gc0 >> 8;
        const float* W    = (mat == 0) ? Wq : (mat == 1) ? Wk : Wv;
        const float* bias = (mat == 0) ? bq : (mat == 1) ? bk : bv;
        short* Out        = (mat == 0) ? Qb : (mat == 1) ? Kb : Vb;
        const int wc0 = gc0 & 255;

        f32x4 acc[4][2] = {};

        const int sr = tid >> 4;
        const int sc4 = (tid & 15) * 4;

        for (int k0 = 0; k0 < 256; k0 += 64) {
            __syncthreads();
#pragma unroll
            for (int it = 0; it < 8; ++it) {
                int row = sr + it * 16;
                float4 v = *reinterpret_cast<const float4*>(&x[(m0 + row) * 256 + k0 + sc4]);
                short4 s4;
                s4.x = f2s(v.x); s4.y = f2s(v.y); s4.z = f2s(v.z); s4.w = f2s(v.w);
                *reinterpret_cast<short4*>(&As[row * 72 + sc4]) = s4;
            }
#pragma unroll
            for (int it = 0; it < 4; ++it) {
                int row = sr + it * 16;
                float4 v = *reinterpret_cast<const float4*>(&W[(wc0 + row) * 256 + k0 + sc4]);
                short4 s4;
                s4.x = f2s(v.x); s4.y = f2s(v.y); s4.z = f2s(v.z); s4.w = f2s(v.w);
                *reinterpret_cast<short4*>(&Bs[row * 72 + sc4]) = s4;
            }
            __syncthreads();
#pragma unroll
            for (int ks = 0; ks < 2; ++ks) {
                const int kb = ks * 32 + g * 8;
                bf16x8 a[4], bfr[2];
#pragma unroll
                for (int i = 0; i < 4; ++i)
                    a[i] = *reinterpret_cast<const bf16x8*>(&As[(wr * 64 + i * 16 + li) * 72 + kb]);
#pragma unroll
                for (int j = 0; j < 2; ++j)
                    bfr[j] = *reinterpret_cast<const bf16x8*>(&Bs[(wc * 32 + j * 16 + li) * 72 + kb]);
#pragma unroll
                for (int i = 0; i < 4; ++i)
#pragma unroll
                    for (int j = 0; j < 2; ++j)
                        acc[i][j] = MFMA16(a[i], bfr[j], acc[i][j]);
            }
        }

#pragma unroll
        for (int j = 0; j < 2; ++j) {
            const int colW = wc0 + wc * 32 + j * 16 + li;
            const int h = colW >> 5, d = colW & 31;
            const float bv_ = bias[colW];
#pragma unroll
            for (int i = 0; i < 4; ++i) {
#pragma unroll
                for (int r = 0; r < 4; ++r) {
                    const int row = m0 + wr * 64 + i * 16 + g * 4 + r;
                    const int bb = row >> 10, nq = row & 1023;
                    Out[((bb * 8 + h) * 1024 + nq) * 32 + d] = f2s(acc[i][j][r] + bv_);
                }
            }
        }
    } else {
        const int gx = bx - 768;               // 0..1023
        const int qt = gx & 31;
        const int b  = (gx >> 5) & 7;
        const int j0 = (gx >> 8) * 8;

        const int4* base = reinterpret_cast<const int4*>(
            adj + ((size_t)(b * 1024 + qt * 32)) * 1024);
        unsigned int* outT = adjG + ((size_t)(b * 32 + qt)) * 16 * 512;

        const int t = tid >> 4;
        const int i = (tid >> 1) & 7;
        const int laneb = 32 * (tid & 1);

#pragma unroll
        for (int jj = 0; jj < 8; ++jj) {
            const int j = j0 + jj;
            const int4 c = base[j * 256 + tid];
            const unsigned int packed =
                (unsigned)c.x | ((unsigned)c.y << 8) | ((unsigned)c.z << 16) | ((unsigned)c.w << 24);
            outT[t * 512 + i * 64 + (j + laneb)] = packed;
        }
    }
}

// ---------------------------------------------------------------------------
// Kernel B: edge-biased flash attention — round-8 attn4 (verified @41.6us,
// strides 36/72 = 16B-aligned reads) + three changes:
//  (1) V^T granule XOR-swizzle g' = g ^ (d&7) ^ 2(d>>3): write banks become
//      a bijection onto 32 banks (was 8-bank pileup = the 1.8M conflicts),
//      reads keep round-8 bank behavior and 16B alignment.
//  (2) tree max (depth 5) instead of serial 16-deep chain.
//  (3) defer-max (THR=8, exp2 domain): skip rescale when max doesn't grow.
// ---------------------------------------------------------------------------
__global__ __launch_bounds__(256)
void attn7(const short* __restrict__ Qb, const short* __restrict__ Kb,
           const short* __restrict__ Vb, const unsigned int* __restrict__ adjG,
           const float* __restrict__ edge_emb, short* __restrict__ AO)
{
    __shared__ __align__(16) short Ks[2][64 * 36];   // [row][d], 72B rows
    __shared__ __align__(16) short Vt[2][32 * 72];   // [d][krow] granule-swizzled
    __shared__ float Etab[8];

    const int tid = threadIdx.x, lane = tid & 63, wid = tid >> 6;
    const int l5 = lane & 31, h32 = lane >> 5;

    // bijective chunked XCD swizzle (512 blocks = 8 XCD x 64)
    const int orig = blockIdx.x + blockIdx.y * 8;
    const int flat = (orig & 7) * 64 + (orig >> 3);
    const int qb = flat & 7, bh = flat >> 3;
    const int b = bh >> 3, h = bh & 7;
    const int qt = qb * 4 + wid;         // wave's q-tile (0..31)
    const int q  = qt * 32 + l5;

    const short* Qh = Qb + bh * (1024 * 32);
    const short* Kh = Kb + bh * (1024 * 32);
    const short* Vh = Vb + bh * (1024 * 32);
    const unsigned int* adjT = adjG + ((size_t)(b * 32 + qt)) * 16 * 512;

    if (tid < 5) Etab[tid] = __expf(edge_emb[tid * 8 + h]);

    // Q fragments (B-operand): col=q=l5, k(d) = c*16 + h32*8 + j
    const bf16x8 qf0 = *reinterpret_cast<const bf16x8*>(&Qh[q * 32 + h32 * 8]);
    const bf16x8 qf1 = *reinterpret_cast<const bf16x8*>(&Qh[q * 32 + 16 + h32 * 8]);

    const float c1 = 0.25503486f;   // log2(e)/sqrt(32)
    const f32x16 zero16 = {};

    f32x16 o = {};
    float m2 = -1e30f, l_run = 0.f;

    // staging map: thread -> (k-row sr = tid>>2, 16B chunk sc = (tid&3)*8)
    const int sr = tid >> 2;
    const int sc = (tid & 3) * 8;
    const int srh = sr >> 3, srl = sr & 7;     // V-swizzle components
    const int scg2 = (sc >> 3) << 1;

    // prologue: load + write tile 0 into buffer 0
    {
        int4 kr = *reinterpret_cast<const int4*>(&Kh[sr * 32 + sc]);
        int4 vr = *reinterpret_cast<const int4*>(&Vh[sr * 32 + sc]);
        short* kd = &Ks[0][sr * 36 + sc];
        *reinterpret_cast<short4*>(kd)     = *reinterpret_cast<short4*>(&kr);
        *reinterpret_cast<short4*>(kd + 4) = *(reinterpret_cast<short4*>(&kr) + 1);
        const short* vs = reinterpret_cast<const short*>(&vr);
#pragma unroll
        for (int i = 0; i < 8; ++i) {
            const int swz = srh ^ i ^ scg2;
            Vt[0][(sc + i) * 72 + swz * 8 + srl] = vs[i];
        }
    }
    __syncthreads();

    for (int t = 0; t < 16; ++t) {
        const int cur = t & 1;
        const int k0 = t * 64;

        // ---- issue next-tile global loads (hidden under compute) ----
        int4 kn, vn;
        if (t < 15) {
            kn = *reinterpret_cast<const int4*>(&Kh[(k0 + 64 + sr) * 32 + sc]);
            vn = *reinterpret_cast<const int4*>(&Vh[(k0 + 64 + sr) * 32 + sc]);
        }

        // ---- adj loads (coalesced gathered layout) ----
        unsigned int a4[8];
#pragma unroll
        for (int i = 0; i < 8; ++i)
            a4[i] = adjT[t * 512 + i * 64 + lane];

        // ---- QK^T from LDS K frags: S^T[k][q] ----
        f32x16 s[2];
#pragma unroll
        for (int ks = 0; ks < 2; ++ks) {
            union { short4 h4[2]; bf16x8 v; } kfa, kfb;
            const int rowb = (ks * 32 + l5) * 36;
            kfa.h4[0] = *reinterpret_cast<const short4*>(&Ks[cur][rowb + h32 * 8]);
            kfa.h4[1] = *reinterpret_cast<const short4*>(&Ks[cur][rowb + h32 * 8 + 4]);
            kfb.h4[0] = *reinterpret_cast<const short4*>(&Ks[cur][rowb + 16 + h32 * 8]);
            kfb.h4[1] = *reinterpret_cast<const short4*>(&Ks[cur][rowb + 16 + h32 * 8 + 4]);
            s[ks] = MFMA32(kfa.v, qf0, zero16);
            s[ks] = MFMA32(kfb.v, qf1, s[ks]);
        }

        // ---- tile max: balanced tree (depth 5) ----
        float mt[16];
#pragma unroll
        for (int r = 0; r < 16; ++r) mt[r] = fmaxf(s[0][r], s[1][r]);
#pragma unroll
        for (int st = 8; st > 0; st >>= 1)
#pragma unroll
            for (int r = 0; r < st; ++r) mt[r] = fmaxf(mt[r], mt[r + st]);
        float tm = mt[0];
        tm = fmaxf(tm, __shfl_xor(tm, 32));
        const float tb = tm * c1;

        // ---- defer-max: only rescale when the max actually grows ----
        if (!__all(tb <= m2 + 8.0f)) {
            const float m2n = fmaxf(m2, tb);
            const float resc = exp2f_fast(m2 - m2n);
            m2 = m2n;
            l_run *= resc;
#pragma unroll
            for (int r = 0; r < 16; ++r) o[r] *= resc;
        }
        const float negm2 = -m2;

        // ---- p = exp2(s*c1 - m2) * E[adj]; pack bf16 pairs ----
        unsigned int pw[2][8];
        float lsum = 0.f;
#pragma unroll
        for (int ks = 0; ks < 2; ++ks) {
#pragma unroll
            for (int rg = 0; rg < 4; ++rg) {
                const unsigned int aw4 = a4[ks * 4 + rg] << 2;
                float pv[4];
#pragma unroll
                for (int j = 0; j < 4; ++j) {
                    const float Ev = *reinterpret_cast<const float*>(
                        reinterpret_cast<const char*>(&Etab[0]) +
                        ((aw4 >> (8 * j)) & 0x3FCu));
                    const float pe = exp2f_fast(fmaf(s[ks][rg * 4 + j], c1, negm2));
                    const float pp = pe * Ev;
                    pv[j] = pp;
                    lsum += pp;
                }
                pw[ks][rg * 2 + 0] = cvtpk(pv[0], pv[1]);
                pw[ks][rg * 2 + 1] = cvtpk(pv[2], pv[3]);
            }
        }
        lsum += __shfl_xor(lsum, 32);
        l_run += lsum;

        // ---- PV: O^T += V^T . P^T  (verified shfl exchange; swizzled V read) ----
#pragma unroll
        for (int kc = 0; kc < 4; ++kc) {
            const int ks = kc >> 1, half = kc & 1;
            const unsigned int A0 = pw[ks][4 * half + 0], A1 = pw[ks][4 * half + 1];
            const unsigned int B0 = pw[ks][4 * half + 2], B1 = pw[ks][4 * half + 3];
            const unsigned int send0 = h32 ? A0 : B0, send1 = h32 ? A1 : B1;
            const unsigned int rv0 = __shfl_xor(send0, 32);
            const unsigned int rv1 = __shfl_xor(send1, 32);
            const unsigned int own0 = h32 ? B0 : A0, own1 = h32 ? B1 : A1;
            union { unsigned int u[4]; bf16x8 v; } P;
            P.u[0] = h32 ? rv0 : own0;
            P.u[1] = h32 ? rv1 : own1;
            P.u[2] = h32 ? own0 : rv0;
            P.u[3] = h32 ? own1 : rv1;
            const int swzr = (kc * 2 + h32) ^ (l5 & 7) ^ ((l5 >> 3) << 1);
            bf16x8 vf = *reinterpret_cast<const bf16x8*>(
                &Vt[cur][l5 * 72 + swzr * 8]);
            o = MFMA32(vf, P.v, o);
        }

        // ---- write next tile into other buffer; single barrier per iter ----
        if (t < 15) {
            short* kd = &Ks[cur ^ 1][sr * 36 + sc];
            *reinterpret_cast<short4*>(kd)     = *reinterpret_cast<short4*>(&kn);
            *reinterpret_cast<short4*>(kd + 4) = *(reinterpret_cast<short4*>(&kn) + 1);
            const short* vs = reinterpret_cast<const short*>(&vn);
#pragma unroll
            for (int i = 0; i < 8; ++i) {
                const int swz = srh ^ i ^ scg2;
                Vt[cur ^ 1][(sc + i) * 72 + swz * 8 + srl] = vs[i];
            }
            __syncthreads();
        }
    }

    // ---- epilogue: every wave writes its own q-tile ----
    const float inv = 1.0f / l_run;
    short* dst = &AO[((size_t)(b * 1024 + q)) * 256 + h * 32];
#pragma unroll
    for (int rg = 0; rg < 4; ++rg) {
        short4 s4;
        s4.x = f2s(o[rg * 4 + 0] * inv);
        s4.y = f2s(o[rg * 4 + 1] * inv);
        s4.z = f2s(o[rg * 4 + 2] * inv);
        s4.w = f2s(o[rg * 4 + 3] * inv);
        *reinterpret_cast<short4*>(&dst[rg * 8 + h32 * 4]) = s4;
    }
}

// ---------------------------------------------------------------------------
// Kernel C: output projection (unchanged, verified).
// ---------------------------------------------------------------------------
__global__ __launch_bounds__(256)
void out_gemm(const short* __restrict__ AO, const float* __restrict__ Wo,
              const float* __restrict__ bo, float* __restrict__ out)
{
    __shared__ short As[128 * 72];
    __shared__ short Bs[64 * 72];

    const int tid = threadIdx.x, lane = tid & 63, wid = tid >> 6;
    const int wr = wid >> 1, wcn = wid & 1;
    const int g = lane >> 4, li = lane & 15;
    const int m0 = blockIdx.x * 128, n0 = blockIdx.y * 64;

    f32x4 acc[4][2] = {};
    const int ar = tid >> 3, ac8 = (tid & 7) * 8;
    const int br = tid >> 4, bc4 = (tid & 15) * 4;

    for (int k0 = 0; k0 < 256; k0 += 64) {
        __syncthreads();
#pragma unroll
        for (int it = 0; it < 4; ++it) {
            int row = ar + it * 32;
            *reinterpret_cast<int4*>(&As[row * 72 + ac8]) =
                *reinterpret_cast<const int4*>(&AO[(m0 + row) * 256 + k0 + ac8]);
        }
#pragma unroll
        for (int it = 0; it < 4; ++it) {
            int row = br + it * 16;
            float4 v = *reinterpret_cast<const float4*>(&Wo[(n0 + row) * 256 + k0 + bc4]);
            short4 s4; s4.x = f2s(v.x); s4.y = f2s(v.y); s4.z = f2s(v.z); s4.w = f2s(v.w);
            *reinterpret_cast<short4*>(&Bs[row * 72 + bc4]) = s4;
        }
        __syncthreads();
#pragma unroll
        for (int ks = 0; ks < 2; ++ks) {
            const int kb = ks * 32 + g * 8;
            bf16x8 a[4], bb[2];
#pragma unroll
            for (int i = 0; i < 4; ++i)
                a[i] = *reinterpret_cast<const bf16x8*>(&As[(wr * 64 + i * 16 + li) * 72 + kb]);
#pragma unroll
            for (int j = 0; j < 2; ++j)
                bb[j] = *reinterpret_cast<const bf16x8*>(&Bs[(wcn * 32 + j * 16 + li) * 72 + kb]);
#pragma unroll
            for (int i = 0; i < 4; ++i)
#pragma unroll
                for (int j = 0; j < 2; ++j)
                    acc[i][j] = MFMA16(a[i], bb[j], acc[i][j]);
        }
    }
#pragma unroll
    for (int j = 0; j < 2; ++j) {
        const int col = n0 + wcn * 32 + j * 16 + li;
        const float bv_ = bo[col];
#pragma unroll
        for (int i = 0; i < 4; ++i)
#pragma unroll
            for (int r = 0; r < 4; ++r) {
                const int row = m0 + wr * 64 + i * 16 + g * 4 + r;
                out[row * 256 + col] = acc[i][j][r] + bv_;
            }
    }
}

extern "C" void kernel_launch(void* const* d_in, const int* in_sizes, int n_in,
                              void* d_out, int out_size, void* d_ws, size_t ws_size,
                              hipStream_t stream)
{
    const float* x  = (const float*)d_in[0];
    const int*   adj = (const int*)d_in[1];
    const float* Wq = (const float*)d_in[2];
    const float* bq = (const float*)d_in[3];
    const float* Wk = (const float*)d_in[4];
    const float* bk = (const float*)d_in[5];
    const float* Wv = (const float*)d_in[6];
    const float* bv = (const float*)d_in[7];
    const float* Wo = (const float*)d_in[8];
    const float* bo = (const float*)d_in[9];
    const float* ee = (const float*)d_in[10];
    float* out = (float*)d_out;

    // Workspace: Qb/Kb/Vb [64][1024][32] bf16 (4MB each), AO [8192][256] bf16 (4MB),
    // adjG [8][32][16][8][64] u32 (8MB)  -> 24MB total (known-good budget)
    short* Qb = (short*)d_ws;
    short* Kb = Qb + 2 * 1024 * 1024;
    short* Vb = Kb + 2 * 1024 * 1024;
    short* AO = Vb + 2 * 1024 * 1024;
    unsigned int* adjG = (unsigned int*)(AO + 2 * 1024 * 1024);

    qkv_and_gather<<<1792, 256, 0, stream>>>(x, Wq, bq, Wk, bk, Wv, bv,
                                             Qb, Kb, Vb, adj, adjG);
    attn7<<<dim3(8, 64), 256, 0, stream>>>(Qb, Kb, Vb, adjG, ee, AO);
    out_gemm<<<dim3(64, 4), 256, 0, stream>>>(AO, Wo, bo, out);
}